// Round 1
// 205.803 us; speedup vs baseline: 1.1113x; 1.1113x over previous
//
#include <hip/hip_runtime.h>
#include <hip/hip_bf16.h>

// VolatilityModulatedAttention: B=2, S=4096, H=512, NH=8, HD=64
// Round 7: attn rebuilt — P never touches LDS. K rows are staged into Ksh in a
// permuted order (bit-shuffle of the DMA source row) chosen so the QK MFMA
// output fragment, packed to bf16, IS the PV A-fragment directly. k is a
// reduction axis so any k-permutation is legal as long as V columns stay
// linear and the distance term is remapped per-slot. QPsh dropped (Q frags
// loaded直接 from global, qscale folded) -> LDS 51200->32768 B -> 4 blocks/CU
// fully resident. Risk term moved into MFMA C-in. setprio(1) around PV MFMAs.

#define S_LEN 4096
#define NHEAD 8
#define HD 64
#define HTOT 512

typedef __attribute__((ext_vector_type(8))) short short8;
typedef __attribute__((ext_vector_type(4))) float floatx4;
typedef __attribute__((ext_vector_type(2))) _Float16 half2v;

#if __has_builtin(__builtin_amdgcn_exp2f)
#define EXP2F(x) __builtin_amdgcn_exp2f(x)
#else
#define EXP2F(x) exp2f(x)
#endif

__device__ __forceinline__ unsigned pack_bf16(float a, float b) {
    unsigned ua = __builtin_bit_cast(unsigned, a) + 0x8000u;
    unsigned ub = __builtin_bit_cast(unsigned, b) + 0x8000u;
    return __builtin_amdgcn_perm(ub, ua, 0x07060302u);
}

__device__ __forceinline__ unsigned short f2bf(float x) {
    unsigned u = __builtin_bit_cast(unsigned, x) + 0x8000u;
    return (unsigned short)(u >> 16);
}

__device__ __forceinline__ void async16(const unsigned short* g, unsigned short* l) {
    __builtin_amdgcn_global_load_lds(
        (const __attribute__((address_space(1))) unsigned int*)g,
        (__attribute__((address_space(3))) unsigned int*)l, 16, 0, 0);
}

// ---------------------------------------------------------------------------
// Fused prepass. [0,2048): K fp32->bf16. [2048,3072): V per-head transpose
// Vt[B*8][64][4096]. [3072,3200): W fp32->bf16.  (unchanged R6)
// ---------------------------------------------------------------------------
__global__ __launch_bounds__(256) void prep_kernel(
    const float* __restrict__ K, unsigned short* __restrict__ K16,
    const float* __restrict__ V, unsigned short* __restrict__ Vt,
    const float* __restrict__ W, unsigned short* __restrict__ W16)
{
    const int tid = threadIdx.x;
    if (blockIdx.x >= 3072) {
        size_t i = ((size_t)(blockIdx.x - 3072) * 256 + tid) * 8;
        float4 a = *(const float4*)(W + i);
        float4 b = *(const float4*)(W + i + 4);
        unsigned o[4] = {pack_bf16(a.x, a.y), pack_bf16(a.z, a.w),
                         pack_bf16(b.x, b.y), pack_bf16(b.z, b.w)};
        *(short8*)(W16 + i) = *(short8*)o;
    } else if (blockIdx.x < 2048) {
        size_t i = ((size_t)blockIdx.x * 256 + tid) * 8;
        float4 a = *(const float4*)(K + i);
        float4 b = *(const float4*)(K + i + 4);
        unsigned o[4] = {pack_bf16(a.x, a.y), pack_bf16(a.z, a.w),
                         pack_bf16(b.x, b.y), pack_bf16(b.z, b.w)};
        *(short8*)(K16 + i) = *(short8*)o;
    } else {
        __shared__ unsigned short T[64 * 66];   // [d][s]
        const int blk = blockIdx.x - 2048;
        const int st = blk & 63;
        const int bh = blk >> 6;
        const int b = bh >> 3, h = bh & 7;
        const float* src = V + ((size_t)b * S_LEN + st * 64) * HTOT + h * HD;
        for (int i = 0; i < 4; i++) {
            int idx = tid + i * 256;
            int s = idx >> 4, c4 = idx & 15;
            float4 v = *(const float4*)(src + (size_t)s * HTOT + c4 * 4);
            T[(c4 * 4 + 0) * 66 + s] = f2bf(v.x);
            T[(c4 * 4 + 1) * 66 + s] = f2bf(v.y);
            T[(c4 * 4 + 2) * 66 + s] = f2bf(v.z);
            T[(c4 * 4 + 3) * 66 + s] = f2bf(v.w);
        }
        __syncthreads();
        unsigned short* dst = Vt + ((size_t)bh * 64) * S_LEN + st * 64;
        for (int i = 0; i < 2; i++) {
            int idx = tid + i * 256;
            int d = idx >> 3, c8 = idx & 7;
            uint2 lo = *(const uint2*)&T[d * 66 + c8 * 8];
            uint2 hi = *(const uint2*)&T[d * 66 + c8 * 8 + 4];
            unsigned o[4] = {lo.x, lo.y, hi.x, hi.y};
            *(short8*)(dst + (size_t)d * S_LEN + c8 * 8) = *(short8*)o;
        }
    }
}

// ---------------------------------------------------------------------------
// Flash attention, K-split x2, double-buffered DMA. Grid: 1024.
// P stays in registers: Ksh row R holds global K row kbase + c(R) where
// c(R) = bits [b5 | b3 b2 | b4 | b1 b0]  (R = [b5 | b4 | b3 b2 | b1 b0]),
// so QK slot (jt,quad,r) scores against k = kbase + (jt>>1)*32 + quad*8 +
// (jt&1)*4 + r — exactly PV A-fragment slot (part=jt>>1, quad, e=(jt&1)*4+r).
// Packed exp2 words in jt-order == pf[nt][part]. V columns stay linear.
// ---------------------------------------------------------------------------
__global__ __launch_bounds__(256, 4) void attn_kernel(
    const float* __restrict__ Q, const unsigned short* __restrict__ K16,
    const unsigned short* __restrict__ Vt,
    const float* __restrict__ risk_sigma, const float* __restrict__ risk_lambda,
    _Float16* __restrict__ Cpart, float* __restrict__ Lpart)
{
    __shared__ unsigned short Ksh[2][64 * 64];
    __shared__ unsigned short Vsh[2][64 * 64];

    const int tid  = threadIdx.x;
    const int wave = tid >> 6;
    const int lane = tid & 63;
    const int quad = lane >> 4;
    const int ln   = lane & 15;
    const int sw   = ln & 7;

    const int bid = blockIdx.x;                 // = ((b*8+h)*32+qt)*2+ks
    const int ks  = bid & 1;
    const int qt  = (bid >> 1) & 31;
    const int h   = (bid >> 6) & 7;
    const int b   = bid >> 9;
    const int qbase = qt * 128;

    float sig = risk_sigma[b];
    sig = fminf(fmaxf(sig, 0.001f), 0.2f);
    const float sn   = (sig - 0.001f) * (1.0f / 0.199f);
    const float coef = risk_lambda[0] * 0.1f * sn;
    const float nc2 = -coef * (1.0f / 4096.0f) * (1.0f / 4096.0f) * 1.4426950408889634f;
    const float qscale = 0.125f * 1.4426950408889634f;

    const float* Qb = Q + (size_t)b * S_LEN * HTOT + (size_t)h * HD;
    const unsigned short* Kb = K16 + (size_t)b * S_LEN * HTOT + (size_t)h * HD;
    const unsigned short* Vb = Vt + ((size_t)(b * 8 + h) * 64) * S_LEN;

    const int rl  = lane >> 3;
    const int c8g = ((lane & 7) ^ rl) << 3;
    // permuted K source row for LDS dest row rr = wave*8+rl (and rr+32):
    // src = [r3 r2 r4 r1 r0] of rr's low 5 bits
    const int ksrow = ((wave & 1) << 4) | (((rl >> 2) & 1) << 3)
                    | ((wave >> 1) << 2) | (rl & 3);

    auto dma = [&](int buf, int kb) {
        const unsigned short* gv = Vb + (size_t)(wave * 8 + rl) * S_LEN + kb + c8g;
        async16(Kb + (size_t)(kb + ksrow) * HTOT + c8g,
                &Ksh[buf][wave * 512 + lane * 8]);
        async16(Kb + (size_t)(kb + 32 + ksrow) * HTOT + c8g,
                &Ksh[buf][(wave + 4) * 512 + lane * 8]);
        async16(gv,              &Vsh[buf][wave * 512 + lane * 8]);
        async16(gv + 32 * S_LEN, &Vsh[buf][(wave + 4) * 512 + lane * 8]);
    };

    dma(0, ks * 2048);

    // Q fragments straight from global (once per block), qscale folded.
    // Row = qbase + wave*32 + nt*16 + ln, cols half*32 + quad*8 .. +7.
    short8 qf[2][2];
    {
        const float* qp0 = Qb + (size_t)(qbase + wave * 32 + ln) * HTOT + quad * 8;
        #pragma unroll
        for (int nt = 0; nt < 2; nt++) {
            const float* qp = qp0 + (size_t)(nt * 16) * HTOT;
            #pragma unroll
            for (int half = 0; half < 2; half++) {
                float4 x = *(const float4*)(qp + half * 32);
                float4 y = *(const float4*)(qp + half * 32 + 4);
                unsigned o[4] = {pack_bf16(x.x * qscale, x.y * qscale),
                                 pack_bf16(x.z * qscale, x.w * qscale),
                                 pack_bf16(y.x * qscale, y.y * qscale),
                                 pack_bf16(y.z * qscale, y.w * qscale)};
                qf[nt][half] = *(short8*)o;
            }
        }
    }
    __syncthreads();   // drains dma(0) (barrier implies vmcnt(0))

    const short sone = (short)0x3F80;
    const short8 ones = {sone, sone, sone, sone, sone, sone, sone, sone};

    floatx4 Oacc[2][4], Lacc[2];
    #pragma unroll
    for (int nt = 0; nt < 2; nt++) {
        Lacc[nt] = (floatx4){0.f, 0.f, 0.f, 0.f};
        #pragma unroll
        for (int dt = 0; dt < 4; dt++) Oacc[nt][dt] = (floatx4){0.f, 0.f, 0.f, 0.f};
    }

    const int qa = qbase + wave * 32;
    const float quad8f = (float)(quad * 8);

    for (int kt = 0; kt < 32; ++kt) {
        const int kbase = ks * 2048 + kt * 64;
        const int cur = kt & 1;
        if (kt < 31) dma(1 - cur, kbase + 64);
        const unsigned short* Kc = Ksh[cur];
        const unsigned short* Vc = Vsh[cur];

        const float dqq = (float)(qa + ln - kbase) - quad8f;
        unsigned pw[2][2][4];   // [nt][part][word] — the PV A-fragments

        #pragma unroll
        for (int jt = 0; jt < 4; jt++) {
            const int krow = (jt * 16 + ln) * 64;
            short8 ak0 = *(const short8*)&Kc[krow + ((quad ^ sw) << 3)];
            short8 ak1 = *(const short8*)&Kc[krow + (((quad + 4) ^ sw) << 3)];
            const float jtoff = (float)((jt >> 1) * 32 + (jt & 1) * 4);
            #pragma unroll
            for (int nt = 0; nt < 2; nt++) {
                // risk term as MFMA C-in: rk[r] = nc2 * d^2, d = q_pos - k_pos
                float d = dqq + ((float)(nt * 16) - jtoff);
                floatx4 rk;
                #pragma unroll
                for (int r = 0; r < 4; r++) {
                    rk[r] = (nc2 * d) * d;
                    d -= 1.0f;
                }
                floatx4 s = __builtin_amdgcn_mfma_f32_16x16x32_bf16(ak0, qf[nt][0], rk, 0, 0, 0);
                s = __builtin_amdgcn_mfma_f32_16x16x32_bf16(ak1, qf[nt][1], s, 0, 0, 0);
                float p0 = EXP2F(s[0]);
                float p1 = EXP2F(s[1]);
                float p2 = EXP2F(s[2]);
                float p3 = EXP2F(s[3]);
                pw[nt][jt >> 1][(jt & 1) * 2 + 0] = pack_bf16(p0, p1);
                pw[nt][jt >> 1][(jt & 1) * 2 + 1] = pack_bf16(p2, p3);
            }
        }

        __builtin_amdgcn_s_setprio(1);
        #pragma unroll
        for (int dt = 0; dt < 4; dt++) {
            const int vrow = (dt * 16 + ln) * 64;
            short8 bv0 = *(const short8*)&Vc[vrow + ((quad ^ sw) << 3)];
            short8 bv1 = *(const short8*)&Vc[vrow + (((quad + 4) ^ sw) << 3)];
            #pragma unroll
            for (int nt = 0; nt < 2; nt++) {
                short8 pa0 = *(const short8*)&pw[nt][0][0];
                short8 pa1 = *(const short8*)&pw[nt][1][0];
                Oacc[nt][dt] = __builtin_amdgcn_mfma_f32_16x16x32_bf16(pa0, bv0, Oacc[nt][dt], 0, 0, 0);
                Oacc[nt][dt] = __builtin_amdgcn_mfma_f32_16x16x32_bf16(pa1, bv1, Oacc[nt][dt], 0, 0, 0);
            }
        }
        #pragma unroll
        for (int nt = 0; nt < 2; nt++) {
            short8 pa0 = *(const short8*)&pw[nt][0][0];
            short8 pa1 = *(const short8*)&pw[nt][1][0];
            Lacc[nt] = __builtin_amdgcn_mfma_f32_16x16x32_bf16(pa0, ones, Lacc[nt], 0, 0, 0);
            Lacc[nt] = __builtin_amdgcn_mfma_f32_16x16x32_bf16(pa1, ones, Lacc[nt], 0, 0, 0);
        }
        __builtin_amdgcn_s_setprio(0);
        __syncthreads();
    }

    _Float16* Cw = Cpart + (size_t)bid * (128 * 64);
    for (int nt = 0; nt < 2; nt++) {
        if (ln == 0) {
            #pragma unroll
            for (int r = 0; r < 4; r++)
                Lpart[bid * 128 + wave * 32 + nt * 16 + quad * 4 + r] = Lacc[nt][r];
        }
        float rl4[4];
        #pragma unroll
        for (int r = 0; r < 4; r++) rl4[r] = 1.0f / Lacc[nt][r];
        for (int dt = 0; dt < 4; dt++)
            #pragma unroll
            for (int r = 0; r < 4; r++) {
                int q = wave * 32 + nt * 16 + quad * 4 + r;
                Cw[q * 64 + dt * 16 + ln] = (_Float16)(Oacc[nt][dt][r] * rl4[r]);
            }
    }
}

// ---------------------------------------------------------------------------
// Combine: ctx = w0*C0 + w1*C1, w_ks = l_ks/(l0+l1). Grid 512 tiles. (unchanged)
// ---------------------------------------------------------------------------
__global__ __launch_bounds__(256) void combine_kernel(
    const _Float16* __restrict__ Cpart, const float* __restrict__ Lpart,
    unsigned short* __restrict__ ctx)
{
    const int t = threadIdx.x;
    const int tile = blockIdx.x;              // (b*8+h)*32+qt
    const int qt = tile & 31, h = (tile >> 5) & 7, b = tile >> 8;
    __shared__ float w0s[128], w1s[128];
    if (t < 128) {
        float l0 = Lpart[(tile * 2 + 0) * 128 + t];
        float l1 = Lpart[(tile * 2 + 1) * 128 + t];
        float inv = 1.0f / (l0 + l1);
        w0s[t] = l0 * inv;
        w1s[t] = l1 * inv;
    }
    __syncthreads();
    const _Float16* C0 = Cpart + (size_t)(tile * 2) * (128 * 64);
    const _Float16* C1 = C0 + 128 * 64;
    for (int i = 0; i < 8; i++) {
        int e = (i * 256 + t) * 4;
        int q = e >> 6, d = e & 63;
        half2v a0 = *(const half2v*)(C0 + e);
        half2v a1 = *(const half2v*)(C0 + e + 2);
        half2v b0 = *(const half2v*)(C1 + e);
        half2v b1 = *(const half2v*)(C1 + e + 2);
        float w0 = w0s[q], w1 = w1s[q];
        float v0 = w0 * (float)a0[0] + w1 * (float)b0[0];
        float v1 = w0 * (float)a0[1] + w1 * (float)b0[1];
        float v2 = w0 * (float)a1[0] + w1 * (float)b1[0];
        float v3 = w0 * (float)a1[1] + w1 * (float)b1[1];
        uint2 o;
        o.x = pack_bf16(v0, v1);
        o.y = pack_bf16(v2, v3);
        *(uint2*)&ctx[((size_t)b * S_LEN + qt * 128 + q) * HTOT + h * HD + d] = o;
    }
}

// ---------------------------------------------------------------------------
// Projection GEMM, all-bf16, DMA double-buffered staging. (unchanged)
// ---------------------------------------------------------------------------
__global__ __launch_bounds__(256) void proj_kernel(
    const unsigned short* __restrict__ A,   // ctx bf16 [8192 x 512]
    const unsigned short* __restrict__ W16, // [512 x 512] bf16
    const float* __restrict__ bias,
    float* __restrict__ out)
{
    __shared__ unsigned short Ash[2][64 * 32];
    __shared__ unsigned short Bsh[2][128 * 32];
    const int tid = threadIdx.x;
    const int wave = tid >> 6, lane = tid & 63, quad = lane >> 4, ln = lane & 15;
    const int wr = wave >> 1, wc = wave & 1;
    const int m0 = blockIdx.y * 64;
    const int nb = blockIdx.x * 128;

    const int arow = (wave * 64 + lane) >> 2;
    const int ac   = (wave * 64 + lane) & 3;
    const int acs  = (ac ^ ((arow >> 1) & 3)) << 3;
    const int wrow0 = (wave * 64 + lane) >> 2;
    const int wc0   = (wave * 64 + lane) & 3;
    const int wcs0  = (wc0 ^ ((wrow0 >> 1) & 3)) << 3;
    const int wrow1 = wrow0 + 64;
    const int wcs1  = (wc0 ^ ((wrow1 >> 1) & 3)) << 3;

    auto dma = [&](int buf, int k0) {
        async16(A + (size_t)(m0 + arow) * 512 + k0 + acs,
                &Ash[buf][wave * 512 + lane * 8]);
        async16(W16 + (size_t)(nb + wrow0) * 512 + k0 + wcs0,
                &Bsh[buf][wave * 512 + lane * 8]);
        async16(W16 + (size_t)(nb + wrow1) * 512 + k0 + wcs1,
                &Bsh[buf][(wave + 4) * 512 + lane * 8]);
    };

    floatx4 acc[2][4];
    for (int i = 0; i < 2; i++)
        for (int j = 0; j < 4; j++) acc[i][j] = (floatx4){0.f, 0.f, 0.f, 0.f};

    dma(0, 0);
    for (int kt = 0; kt < 16; ++kt) {
        const int cur = kt & 1;
        __syncthreads();
        if (kt < 15) dma(1 - cur, (kt + 1) * 32);

        short8 af[2], bf[4];
        for (int i = 0; i < 2; i++) {
            int r = wr * 32 + i * 16 + ln;
            af[i] = *(const short8*)&Ash[cur][r * 32 + ((quad ^ ((r >> 1) & 3)) << 3)];
        }
        for (int j = 0; j < 4; j++) {
            int r = wc * 64 + j * 16 + ln;
            bf[j] = *(const short8*)&Bsh[cur][r * 32 + ((quad ^ ((r >> 1) & 3)) << 3)];
        }
        for (int i = 0; i < 2; i++)
            for (int j = 0; j < 4; j++)
                acc[i][j] = __builtin_amdgcn_mfma_f32_16x16x32_bf16(af[i], bf[j], acc[i][j], 0, 0, 0);
    }

    for (int i = 0; i < 2; i++) {
        int row = m0 + wr * 32 + i * 16 + quad * 4;
        for (int j = 0; j < 4; j++) {
            int col = nb + wc * 64 + j * 16 + ln;
            float bv = bias[col];
            #pragma unroll
            for (int r = 0; r < 4; r++)
                out[(size_t)(row + r) * 512 + col] = acc[i][j][r] + bv;
        }
    }
}

extern "C" void kernel_launch(void* const* d_in, const int* in_sizes, int n_in,
                              void* d_out, int out_size, void* d_ws, size_t ws_size,
                              hipStream_t stream) {
    const float* Q    = (const float*)d_in[0];
    const float* K    = (const float*)d_in[1];
    const float* V    = (const float*)d_in[2];
    const float* sig  = (const float*)d_in[3];
    const float* lam  = (const float*)d_in[4];
    const float* W    = (const float*)d_in[5];
    const float* bias = (const float*)d_in[6];

    unsigned short* K16 = (unsigned short*)d_ws;                          // 8 MB
    unsigned short* Vt  = (unsigned short*)((char*)d_ws + (8u << 20));    // 8 MB
    unsigned short* ctx = (unsigned short*)((char*)d_ws + (16u << 20));   // 8 MB
    float* Lpart        = (float*)((char*)d_ws + (24u << 20));            // 512 KB
    unsigned short* W16 = (unsigned short*)((char*)d_ws + (24u << 20) + (512u << 10)); // 512 KB
    _Float16* Cpart     = (_Float16*)d_out;   // 16 MB scratch, overwritten by proj
    float* out = (float*)d_out;

    prep_kernel<<<dim3(3200), dim3(256), 0, stream>>>(K, K16, V, Vt, W, W16);
    attn_kernel<<<dim3(1024), dim3(256), 0, stream>>>(Q, K16, Vt, sig, lam, Cpart, Lpart);
    combine_kernel<<<dim3(512), dim3(256), 0, stream>>>(Cpart, Lpart, ctx);
    proj_kernel<<<dim3(4, 128), dim3(256), 0, stream>>>(ctx, W16, bias, out);
}

// Round 3
// 201.329 us; speedup vs baseline: 1.1360x; 1.0222x over previous
//
#include <hip/hip_runtime.h>
#include <hip/hip_bf16.h>

// VolatilityModulatedAttention: B=2, S=4096, H=512, NH=8, HD=64
// Round 9: R8 fusion structure (combine folded into attn: wave-groups 0-3/4-7
// over K-split halves, f32 LDS combine epilogue, direct bf16 ctx write;
// Cpart/Lpart eliminated) with ALL inner-loop arithmetic reverted to the
// R7-validated forms: pack_bf16 (not v_cvt_pk_bf16_f32 — prime suspect of
// R8's absmax failure) and per-r rk computation. prep/proj unchanged.

#define S_LEN 4096
#define NHEAD 8
#define HD 64
#define HTOT 512

typedef __attribute__((ext_vector_type(8))) short short8;
typedef __attribute__((ext_vector_type(4))) float floatx4;

#if __has_builtin(__builtin_amdgcn_exp2f)
#define EXP2F(x) __builtin_amdgcn_exp2f(x)
#else
#define EXP2F(x) exp2f(x)
#endif

__device__ __forceinline__ unsigned pack_bf16(float a, float b) {
    unsigned ua = __builtin_bit_cast(unsigned, a) + 0x8000u;
    unsigned ub = __builtin_bit_cast(unsigned, b) + 0x8000u;
    return __builtin_amdgcn_perm(ub, ua, 0x07060302u);
}

__device__ __forceinline__ unsigned short f2bf(float x) {
    unsigned u = __builtin_bit_cast(unsigned, x) + 0x8000u;
    return (unsigned short)(u >> 16);
}

__device__ __forceinline__ void async16(const unsigned short* g, unsigned short* l) {
    __builtin_amdgcn_global_load_lds(
        (const __attribute__((address_space(1))) unsigned int*)g,
        (__attribute__((address_space(3))) unsigned int*)l, 16, 0, 0);
}

// ---------------------------------------------------------------------------
// Fused prepass. [0,2048): K fp32->bf16. [2048,3072): V per-head transpose
// Vt[B*8][64][4096]. [3072,3200): W fp32->bf16.  (unchanged)
// ---------------------------------------------------------------------------
__global__ __launch_bounds__(256) void prep_kernel(
    const float* __restrict__ K, unsigned short* __restrict__ K16,
    const float* __restrict__ V, unsigned short* __restrict__ Vt,
    const float* __restrict__ W, unsigned short* __restrict__ W16)
{
    const int tid = threadIdx.x;
    if (blockIdx.x >= 3072) {
        size_t i = ((size_t)(blockIdx.x - 3072) * 256 + tid) * 8;
        float4 a = *(const float4*)(W + i);
        float4 b = *(const float4*)(W + i + 4);
        unsigned o[4] = {pack_bf16(a.x, a.y), pack_bf16(a.z, a.w),
                         pack_bf16(b.x, b.y), pack_bf16(b.z, b.w)};
        *(short8*)(W16 + i) = *(short8*)o;
    } else if (blockIdx.x < 2048) {
        size_t i = ((size_t)blockIdx.x * 256 + tid) * 8;
        float4 a = *(const float4*)(K + i);
        float4 b = *(const float4*)(K + i + 4);
        unsigned o[4] = {pack_bf16(a.x, a.y), pack_bf16(a.z, a.w),
                         pack_bf16(b.x, b.y), pack_bf16(b.z, b.w)};
        *(short8*)(K16 + i) = *(short8*)o;
    } else {
        __shared__ unsigned short T[64 * 66];   // [d][s]
        const int blk = blockIdx.x - 2048;
        const int st = blk & 63;
        const int bh = blk >> 6;
        const int b = bh >> 3, h = bh & 7;
        const float* src = V + ((size_t)b * S_LEN + st * 64) * HTOT + h * HD;
        for (int i = 0; i < 4; i++) {
            int idx = tid + i * 256;
            int s = idx >> 4, c4 = idx & 15;
            float4 v = *(const float4*)(src + (size_t)s * HTOT + c4 * 4);
            T[(c4 * 4 + 0) * 66 + s] = f2bf(v.x);
            T[(c4 * 4 + 1) * 66 + s] = f2bf(v.y);
            T[(c4 * 4 + 2) * 66 + s] = f2bf(v.z);
            T[(c4 * 4 + 3) * 66 + s] = f2bf(v.w);
        }
        __syncthreads();
        unsigned short* dst = Vt + ((size_t)bh * 64) * S_LEN + st * 64;
        for (int i = 0; i < 2; i++) {
            int idx = tid + i * 256;
            int d = idx >> 3, c8 = idx & 7;
            uint2 lo = *(const uint2*)&T[d * 66 + c8 * 8];
            uint2 hi = *(const uint2*)&T[d * 66 + c8 * 8 + 4];
            unsigned o[4] = {lo.x, lo.y, hi.x, hi.y};
            *(short8*)(dst + (size_t)d * S_LEN + c8 * 8) = *(short8*)o;
        }
    }
}

// ---------------------------------------------------------------------------
// Flash attention, K-split internal: wave-groups 0-3 (ks=0) / 4-7 (ks=1) of a
// 512-thread block. Grid: 512 = (b*8+h)*32+qt. P stays in registers (R7
// permuted-K staging). Epilogue: f32 cross-group combine via LDS, direct
// bf16 ctx write. LDS 64KB: [grp][buf][K|V][4096] shorts, reused as
// X[128][68] f32 + Lsh[2][128] in the epilogue.
// ---------------------------------------------------------------------------
__global__ __launch_bounds__(512, 4) void attn_kernel(
    const float* __restrict__ Q, const unsigned short* __restrict__ K16,
    const unsigned short* __restrict__ Vt,
    const float* __restrict__ risk_sigma, const float* __restrict__ risk_lambda,
    unsigned short* __restrict__ ctx)
{
    __shared__ unsigned short SH[32768];   // 64 KiB

    const int tid  = threadIdx.x;
    const int wave = tid >> 6;
    const int grp  = wave >> 2;            // K-split half
    const int wv   = wave & 3;             // wave within group
    const int lane = tid & 63;
    const int quad = lane >> 4;
    const int ln   = lane & 15;
    const int sw   = ln & 7;

    const int bid = blockIdx.x;            // (b*8+h)*32+qt
    const int qt  = bid & 31;
    const int h   = (bid >> 5) & 7;
    const int b   = bid >> 8;
    const int qbase = qt * 128;

    float sig = risk_sigma[b];
    sig = fminf(fmaxf(sig, 0.001f), 0.2f);
    const float sn   = (sig - 0.001f) * (1.0f / 0.199f);
    const float coef = risk_lambda[0] * 0.1f * sn;
    const float nc2 = -coef * (1.0f / 4096.0f) * (1.0f / 4096.0f) * 1.4426950408889634f;
    const float qscale = 0.125f * 1.4426950408889634f;

    const float* Qb = Q + (size_t)b * S_LEN * HTOT + (size_t)h * HD;
    const unsigned short* Kb = K16 + (size_t)b * S_LEN * HTOT + (size_t)h * HD;
    const unsigned short* Vb = Vt + ((size_t)(b * 8 + h) * 64) * S_LEN;

    const int rl  = lane >> 3;
    const int c8g = ((lane & 7) ^ rl) << 3;
    // permuted K source row for LDS dest row rr = wv*8+rl:
    // src = [r3 r2 r4 r1 r0] of rr's low 5 bits (R7 mapping, per group)
    const int ksrow = ((wv & 1) << 4) | (((rl >> 2) & 1) << 3)
                    | ((wv >> 1) << 2) | (rl & 3);

    auto dma = [&](int buf, int kb) {
        unsigned short* base = SH + (grp * 2 + buf) * 8192;   // K at +0, V at +4096
        const unsigned short* gk = Kb + (size_t)(kb + ksrow) * HTOT + c8g;
        const unsigned short* gv = Vb + (size_t)(wv * 8 + rl) * S_LEN + kb + c8g;
        async16(gk,              base + wv * 512 + lane * 8);
        async16(gk + 32 * HTOT,  base + (wv + 4) * 512 + lane * 8);
        async16(gv,              base + 4096 + wv * 512 + lane * 8);
        async16(gv + 32 * S_LEN, base + 4096 + (wv + 4) * 512 + lane * 8);
    };

    const int kb0 = grp * 2048;
    dma(0, kb0);

    // Q fragments straight from global, qscale folded.
    short8 qf[2][2];
    {
        const float* qp0 = Qb + (size_t)(qbase + wv * 32 + ln) * HTOT + quad * 8;
        #pragma unroll
        for (int nt = 0; nt < 2; nt++) {
            const float* qp = qp0 + (size_t)(nt * 16) * HTOT;
            #pragma unroll
            for (int half = 0; half < 2; half++) {
                float4 x = *(const float4*)(qp + half * 32);
                float4 y = *(const float4*)(qp + half * 32 + 4);
                unsigned o[4] = {pack_bf16(x.x * qscale, x.y * qscale),
                                 pack_bf16(x.z * qscale, x.w * qscale),
                                 pack_bf16(y.x * qscale, y.y * qscale),
                                 pack_bf16(y.z * qscale, y.w * qscale)};
                qf[nt][half] = *(short8*)o;
            }
        }
    }
    __syncthreads();   // drains dma(0)

    const short sone = (short)0x3F80;
    const short8 ones = {sone, sone, sone, sone, sone, sone, sone, sone};

    floatx4 Oacc[2][4], Lacc[2];
    #pragma unroll
    for (int nt = 0; nt < 2; nt++) {
        Lacc[nt] = (floatx4){0.f, 0.f, 0.f, 0.f};
        #pragma unroll
        for (int dt = 0; dt < 4; dt++) Oacc[nt][dt] = (floatx4){0.f, 0.f, 0.f, 0.f};
    }

    const int qa = qbase + wv * 32;
    const float quad8f = (float)(quad * 8);

    for (int kt = 0; kt < 32; ++kt) {
        const int kbase = kb0 + kt * 64;
        const int cur = kt & 1;
        if (kt < 31) dma(1 - cur, kbase + 64);
        const unsigned short* Kc = SH + (grp * 2 + cur) * 8192;
        const unsigned short* Vc = Kc + 4096;

        const float dqq = (float)(qa + ln - kbase) - quad8f;
        unsigned pw[2][2][4];   // [nt][part][word] — PV A-fragments

        #pragma unroll
        for (int jt = 0; jt < 4; jt++) {
            const int krow = (jt * 16 + ln) * 64;
            short8 ak0 = *(const short8*)&Kc[krow + ((quad ^ sw) << 3)];
            short8 ak1 = *(const short8*)&Kc[krow + (((quad + 4) ^ sw) << 3)];
            const float jtoff = (float)((jt >> 1) * 32 + (jt & 1) * 4);
            #pragma unroll
            for (int nt = 0; nt < 2; nt++) {
                // risk term as MFMA C-in: rk[r] = nc2*(d0-r)^2 (R7-exact form)
                float d = dqq + ((float)(nt * 16) - jtoff);
                floatx4 rk;
                #pragma unroll
                for (int r = 0; r < 4; r++) {
                    rk[r] = (nc2 * d) * d;
                    d -= 1.0f;
                }
                floatx4 s = __builtin_amdgcn_mfma_f32_16x16x32_bf16(ak0, qf[nt][0], rk, 0, 0, 0);
                s = __builtin_amdgcn_mfma_f32_16x16x32_bf16(ak1, qf[nt][1], s, 0, 0, 0);
                float p0 = EXP2F(s[0]);
                float p1 = EXP2F(s[1]);
                float p2 = EXP2F(s[2]);
                float p3 = EXP2F(s[3]);
                pw[nt][jt >> 1][(jt & 1) * 2 + 0] = pack_bf16(p0, p1);
                pw[nt][jt >> 1][(jt & 1) * 2 + 1] = pack_bf16(p2, p3);
            }
        }

        __builtin_amdgcn_s_setprio(1);
        #pragma unroll
        for (int dt = 0; dt < 4; dt++) {
            const int vrow = (dt * 16 + ln) * 64;
            short8 bv0 = *(const short8*)&Vc[vrow + ((quad ^ sw) << 3)];
            short8 bv1 = *(const short8*)&Vc[vrow + (((quad + 4) ^ sw) << 3)];
            #pragma unroll
            for (int nt = 0; nt < 2; nt++) {
                short8 pa0 = *(const short8*)&pw[nt][0][0];
                short8 pa1 = *(const short8*)&pw[nt][1][0];
                Oacc[nt][dt] = __builtin_amdgcn_mfma_f32_16x16x32_bf16(pa0, bv0, Oacc[nt][dt], 0, 0, 0);
                Oacc[nt][dt] = __builtin_amdgcn_mfma_f32_16x16x32_bf16(pa1, bv1, Oacc[nt][dt], 0, 0, 0);
            }
        }
        #pragma unroll
        for (int nt = 0; nt < 2; nt++) {
            short8 pa0 = *(const short8*)&pw[nt][0][0];
            short8 pa1 = *(const short8*)&pw[nt][1][0];
            Lacc[nt] = __builtin_amdgcn_mfma_f32_16x16x32_bf16(pa0, ones, Lacc[nt], 0, 0, 0);
            Lacc[nt] = __builtin_amdgcn_mfma_f32_16x16x32_bf16(pa1, ones, Lacc[nt], 0, 0, 0);
        }
        __builtin_amdgcn_s_setprio(0);
        __syncthreads();
    }

    // ---- epilogue: cross-group combine in LDS (f32), direct ctx write ----
    float* X   = (float*)SH;               // [128][68] f32, 34816 B
    float* Lsh = (float*)SH + 128 * 68;    // [2][128] f32, +1024 B

    if (ln == 0) {
        #pragma unroll
        for (int nt = 0; nt < 2; nt++)
            #pragma unroll
            for (int r = 0; r < 4; r++)
                Lsh[grp * 128 + wv * 32 + nt * 16 + quad * 4 + r] = Lacc[nt][r];
    }
    if (grp == 0) {
        #pragma unroll
        for (int nt = 0; nt < 2; nt++)
            #pragma unroll
            for (int dt = 0; dt < 4; dt++)
                #pragma unroll
                for (int r = 0; r < 4; r++)
                    X[(wv * 32 + nt * 16 + quad * 4 + r) * 68 + dt * 16 + ln] = Oacc[nt][dt][r];
    }
    __syncthreads();
    if (grp == 1) {
        #pragma unroll
        for (int nt = 0; nt < 2; nt++) {
            float inv[4];
            #pragma unroll
            for (int r = 0; r < 4; r++) {
                int row = wv * 32 + nt * 16 + quad * 4 + r;
                inv[r] = 1.0f / (Lsh[row] + Lsh[128 + row]);
            }
            #pragma unroll
            for (int dt = 0; dt < 4; dt++)
                #pragma unroll
                for (int r = 0; r < 4; r++) {
                    int row = wv * 32 + nt * 16 + quad * 4 + r;
                    float* p = &X[row * 68 + dt * 16 + ln];
                    *p = (*p + Oacc[nt][dt][r]) * inv[r];
                }
        }
    }
    __syncthreads();
    {
        const int q = tid >> 2;            // 128 rows, 4 threads/row
        const int c = tid & 3;             // 16-d chunk
        const float* xp = X + q * 68 + c * 16;
        float4 x0 = *(const float4*)(xp + 0);
        float4 x1 = *(const float4*)(xp + 4);
        float4 x2 = *(const float4*)(xp + 8);
        float4 x3 = *(const float4*)(xp + 12);
        unsigned o0[4] = {pack_bf16(x0.x, x0.y), pack_bf16(x0.z, x0.w),
                          pack_bf16(x1.x, x1.y), pack_bf16(x1.z, x1.w)};
        unsigned o1[4] = {pack_bf16(x2.x, x2.y), pack_bf16(x2.z, x2.w),
                          pack_bf16(x3.x, x3.y), pack_bf16(x3.z, x3.w)};
        unsigned short* cp = ctx + ((size_t)b * S_LEN + qbase + q) * HTOT + h * HD + c * 16;
        *(short8*)cp       = *(short8*)o0;
        *(short8*)(cp + 8) = *(short8*)o1;
    }
}

// ---------------------------------------------------------------------------
// Projection GEMM, all-bf16, DMA double-buffered staging. (unchanged)
// ---------------------------------------------------------------------------
__global__ __launch_bounds__(256) void proj_kernel(
    const unsigned short* __restrict__ A,   // ctx bf16 [8192 x 512]
    const unsigned short* __restrict__ W16, // [512 x 512] bf16
    const float* __restrict__ bias,
    float* __restrict__ out)
{
    __shared__ unsigned short Ash[2][64 * 32];
    __shared__ unsigned short Bsh[2][128 * 32];
    const int tid = threadIdx.x;
    const int wave = tid >> 6, lane = tid & 63, quad = lane >> 4, ln = lane & 15;
    const int wr = wave >> 1, wc = wave & 1;
    const int m0 = blockIdx.y * 64;
    const int nb = blockIdx.x * 128;

    const int arow = (wave * 64 + lane) >> 2;
    const int ac   = (wave * 64 + lane) & 3;
    const int acs  = (ac ^ ((arow >> 1) & 3)) << 3;
    const int wrow0 = (wave * 64 + lane) >> 2;
    const int wc0   = (wave * 64 + lane) & 3;
    const int wcs0  = (wc0 ^ ((wrow0 >> 1) & 3)) << 3;
    const int wrow1 = wrow0 + 64;
    const int wcs1  = (wc0 ^ ((wrow1 >> 1) & 3)) << 3;

    auto dma = [&](int buf, int k0) {
        async16(A + (size_t)(m0 + arow) * 512 + k0 + acs,
                &Ash[buf][wave * 512 + lane * 8]);
        async16(W16 + (size_t)(nb + wrow0) * 512 + k0 + wcs0,
                &Bsh[buf][wave * 512 + lane * 8]);
        async16(W16 + (size_t)(nb + wrow1) * 512 + k0 + wcs1,
                &Bsh[buf][(wave + 4) * 512 + lane * 8]);
    };

    floatx4 acc[2][4];
    for (int i = 0; i < 2; i++)
        for (int j = 0; j < 4; j++) acc[i][j] = (floatx4){0.f, 0.f, 0.f, 0.f};

    dma(0, 0);
    for (int kt = 0; kt < 16; ++kt) {
        const int cur = kt & 1;
        __syncthreads();
        if (kt < 15) dma(1 - cur, (kt + 1) * 32);

        short8 af[2], bf[4];
        for (int i = 0; i < 2; i++) {
            int r = wr * 32 + i * 16 + ln;
            af[i] = *(const short8*)&Ash[cur][r * 32 + ((quad ^ ((r >> 1) & 3)) << 3)];
        }
        for (int j = 0; j < 4; j++) {
            int r = wc * 64 + j * 16 + ln;
            bf[j] = *(const short8*)&Bsh[cur][r * 32 + ((quad ^ ((r >> 1) & 3)) << 3)];
        }
        for (int i = 0; i < 2; i++)
            for (int j = 0; j < 4; j++)
                acc[i][j] = __builtin_amdgcn_mfma_f32_16x16x32_bf16(af[i], bf[j], acc[i][j], 0, 0, 0);
    }

    for (int i = 0; i < 2; i++) {
        int row = m0 + wr * 32 + i * 16 + quad * 4;
        for (int j = 0; j < 4; j++) {
            int col = nb + wc * 64 + j * 16 + ln;
            float bv = bias[col];
            #pragma unroll
            for (int r = 0; r < 4; r++)
                out[(size_t)(row + r) * 512 + col] = acc[i][j][r] + bv;
        }
    }
}

extern "C" void kernel_launch(void* const* d_in, const int* in_sizes, int n_in,
                              void* d_out, int out_size, void* d_ws, size_t ws_size,
                              hipStream_t stream) {
    const float* Q    = (const float*)d_in[0];
    const float* K    = (const float*)d_in[1];
    const float* V    = (const float*)d_in[2];
    const float* sig  = (const float*)d_in[3];
    const float* lam  = (const float*)d_in[4];
    const float* W    = (const float*)d_in[5];
    const float* bias = (const float*)d_in[6];

    unsigned short* K16 = (unsigned short*)d_ws;                          // 8 MB
    unsigned short* Vt  = (unsigned short*)((char*)d_ws + (8u << 20));    // 8 MB
    unsigned short* ctx = (unsigned short*)((char*)d_ws + (16u << 20));   // 8 MB
    unsigned short* W16 = (unsigned short*)((char*)d_ws + (24u << 20));   // 512 KB
    float* out = (float*)d_out;

    prep_kernel<<<dim3(3200), dim3(256), 0, stream>>>(K, K16, V, Vt, W, W16);
    attn_kernel<<<dim3(512), dim3(512), 0, stream>>>(Q, K16, Vt, sig, lam, ctx);
    proj_kernel<<<dim3(4, 128), dim3(256), 0, stream>>>(ctx, W16, bias, out);
}